// Round 1
// baseline (655.741 us; speedup 1.0000x reference)
//
#include <hip/hip_runtime.h>
#include <math.h>

// EquiTritonModel: N=10000 nodes, E=160000 edges, D=32, H=16, NB=16.
// Key algebraic restructurings (see journal):
//  - o1/z1' are dead code (output depends only on z0 path) -> skipped.
//  - Per-edge generated weights wa/wb folded through atom_emb vocabulary (100
//    types): T0/T1[a,j,h] precomputed => per-edge cost 16x16 instead of 16x1024.
//  - Readout folded through fc1: G1/G4[j,h] = sum_k fc1_w2[j, off+h*16+k]*r[k];
//    second segment_sum replaced by flat edge-sum.
// out = 0.25 * sum_n z0[n].r  +  (N0/64) * sum_e [ y0*(s.g1) + (dot.g4) ]

namespace {
constexpr int   NATOMS   = 100;
constexpr float PI_F     = 3.14159265358979323846f;
constexpr float INV4PI_F = 0.28209479177387814f;   // 1/sqrt(4*pi)
constexpr float SQRT3_F  = 1.7320508075688772f;
constexpr float CUT_F    = 6.0f;
constexpr float BASIS_C  = 2.3094010767585034f;    // sqrt(2/6)*sqrt(16)
constexpr float N0_F     = 0.17677669529663687f;   // 1/sqrt(32)
}

__device__ __forceinline__ float silu(float x) {
  return x / (1.0f + expf(-x));
}

__device__ __forceinline__ float block_reduce_sum(float v) {
  #pragma unroll
  for (int o = 32; o > 0; o >>= 1) v += __shfl_down(v, o, 64);
  __shared__ float ls[8];
  int lane = threadIdx.x & 63;
  int w    = threadIdx.x >> 6;
  if (lane == 0) ls[w] = v;
  __syncthreads();
  float s = 0.f;
  if (threadIdx.x == 0) {
    int nw = (blockDim.x + 63) >> 6;
    for (int i = 0; i < nw; ++i) s += ls[i];
  }
  return s;
}

// ---------------------------------------------------------------------------
// Precompute: T0/T1[a,j,h] (100x16x16 each) and G1/G4[j,h] (16x16 each).
// grid = NATOMS+1 blocks x 256 threads. Block NATOMS does G tables.
// ---------------------------------------------------------------------------
__global__ void precompute_kernel(const float* __restrict__ atom_emb,
                                  const float* __restrict__ fc0_w2,
                                  const float* __restrict__ fc1_w2,
                                  const float* __restrict__ w_readout,
                                  float* __restrict__ T0, float* __restrict__ T1,
                                  float* __restrict__ G1, float* __restrict__ G4) {
  int b = blockIdx.x;
  int t = threadIdx.x;           // t = j*16 + h
  int j = t >> 4;
  int h = t & 15;
  if (b < NATOMS) {
    float s0 = 0.f, s1 = 0.f;
    #pragma unroll
    for (int d = 0; d < 32; ++d) {
      float x = atom_emb[b * 32 + d];
      s0 = fmaf(x, fc0_w2[j * 1024 + d * 16 + h], s0);
      s1 = fmaf(x, fc0_w2[j * 1024 + 512 + d * 16 + h], s1);
    }
    T0[b * 256 + t] = s0;
    T1[b * 256 + t] = s1;
  } else {
    float g1 = 0.f, g4 = 0.f;
    #pragma unroll
    for (int k = 0; k < 16; ++k) {
      float r = w_readout[k];
      g1 = fmaf(fc1_w2[j * 1024 + h * 16 + k], r, g1);
      g4 = fmaf(fc1_w2[j * 1024 + 768 + h * 16 + k], r, g4);
    }
    G1[t] = g1;
    G4[t] = g4;
  }
}

// ---------------------------------------------------------------------------
// Phase 1: per edge, compute basis -> h0 -> u0/u1 via T tables, scatter-add
// into z0[dst] (16 floats) and z1[dst] (48 floats).
// z0 stores the reference z0 (including /DEG); z1 likewise.
// ---------------------------------------------------------------------------
__global__ void phase1_kernel(const int* __restrict__ ei,      // [2*E]
                              const float* __restrict__ coords, // [N*3]
                              const int* __restrict__ an,       // [N]
                              const float* __restrict__ fc0_w1, // [16*16]
                              const float* __restrict__ T0,
                              const float* __restrict__ T1,
                              float* __restrict__ z0,
                              float* __restrict__ z1,
                              int E) {
  __shared__ float w1s[256];
  w1s[threadIdx.x] = fc0_w1[threadIdx.x];
  __syncthreads();

  int e = blockIdx.x * blockDim.x + threadIdx.x;
  if (e >= E) return;
  int s = ei[e];
  int d = ei[E + e];

  float vx = coords[3 * s + 0] - coords[3 * d + 0];
  float vy = coords[3 * s + 1] - coords[3 * d + 1];
  float vz = coords[3 * s + 2] - coords[3 * d + 2];
  float dist = sqrtf(vx * vx + vy * vy + vz * vz);
  float inv  = 1.0f / fmaxf(dist, 1e-9f);
  float ux = vx * inv, uy = vy * inv, uz = vz * inv;

  float bc  = (dist < CUT_F) ? (BASIS_C * inv) : 0.0f;
  float basis[16];
  #pragma unroll
  for (int n = 0; n < 16; ++n)
    basis[n] = sinf((float)(n + 1) * PI_F * dist * (1.0f / CUT_F)) * bc;

  float h0[16];
  #pragma unroll
  for (int j = 0; j < 16; ++j) {
    float acc = 0.f;
    #pragma unroll
    for (int n = 0; n < 16; ++n) acc = fmaf(basis[n], w1s[n * 16 + j], acc);
    h0[j] = silu(acc * 0.25f);
  }

  int a = an[s];
  const float4* t0 = (const float4*)(T0 + a * 256);
  const float4* t1 = (const float4*)(T1 + a * 256);
  float u0[16], u1[16];
  #pragma unroll
  for (int h = 0; h < 16; ++h) { u0[h] = 0.f; u1[h] = 0.f; }
  #pragma unroll
  for (int j = 0; j < 16; ++j) {
    float hj = h0[j];
    #pragma unroll
    for (int q = 0; q < 4; ++q) {
      float4 v0 = t0[j * 4 + q];
      float4 v1 = t1[j * 4 + q];
      u0[q * 4 + 0] = fmaf(hj, v0.x, u0[q * 4 + 0]);
      u0[q * 4 + 1] = fmaf(hj, v0.y, u0[q * 4 + 1]);
      u0[q * 4 + 2] = fmaf(hj, v0.z, u0[q * 4 + 2]);
      u0[q * 4 + 3] = fmaf(hj, v0.w, u0[q * 4 + 3]);
      u1[q * 4 + 0] = fmaf(hj, v1.x, u1[q * 4 + 0]);
      u1[q * 4 + 1] = fmaf(hj, v1.y, u1[q * 4 + 1]);
      u1[q * 4 + 2] = fmaf(hj, v1.z, u1[q * 4 + 2]);
      u1[q * 4 + 3] = fmaf(hj, v1.w, u1[q * 4 + 3]);
    }
  }

  // k0 = y0 * n0 * 0.25 (fc0 second-layer /sqrt(16)) * 0.25 (DEG)
  const float k0 = INV4PI_F * N0_F * 0.0625f;
  // k1 = sqrt(3)*y0 * n0 * 0.25 * 0.25 (per unit[m])
  const float k1 = SQRT3_F * INV4PI_F * N0_F * 0.0625f;

  float* z0d = z0 + (size_t)d * 16;
  #pragma unroll
  for (int h = 0; h < 16; ++h) atomicAdd(z0d + h, u0[h] * k0);

  float* z1d = z1 + (size_t)d * 48;
  float cx = k1 * ux, cy = k1 * uy, cz = k1 * uz;
  #pragma unroll
  for (int h = 0; h < 16; ++h) {
    float t = u1[h];
    atomicAdd(z1d + h * 3 + 0, t * cx);
    atomicAdd(z1d + h * 3 + 1, t * cy);
    atomicAdd(z1d + h * 3 + 2, t * cz);
  }
}

// ---------------------------------------------------------------------------
// Phase 2: per edge, recompute basis -> h1, g1/g4 via G tables, gather
// s=z0[src], v=z1[src], reduce scalar contribution, one atomic per block.
// ---------------------------------------------------------------------------
__global__ void phase2_kernel(const int* __restrict__ ei,
                              const float* __restrict__ coords,
                              const float* __restrict__ fc1_w1,
                              const float* __restrict__ G1t,
                              const float* __restrict__ G4t,
                              const float* __restrict__ z0,
                              const float* __restrict__ z1,
                              float* __restrict__ out,
                              int E) {
  __shared__ float w1s[256];
  __shared__ float g1s[256];
  __shared__ float g4s[256];
  w1s[threadIdx.x] = fc1_w1[threadIdx.x];
  g1s[threadIdx.x] = G1t[threadIdx.x];
  g4s[threadIdx.x] = G4t[threadIdx.x];
  __syncthreads();

  int e = blockIdx.x * blockDim.x + threadIdx.x;
  float c = 0.f;
  if (e < E) {
    int s = ei[e];                  // dst not needed: seg-sum folded to total
    float vx = coords[3 * s + 0] - coords[3 * ei[E + e] + 0];
    float vy = coords[3 * s + 1] - coords[3 * ei[E + e] + 1];
    float vz = coords[3 * s + 2] - coords[3 * ei[E + e] + 2];
    float dist = sqrtf(vx * vx + vy * vy + vz * vz);
    float inv  = 1.0f / fmaxf(dist, 1e-9f);
    float ux = vx * inv, uy = vy * inv, uz = vz * inv;

    float bc = (dist < CUT_F) ? (BASIS_C * inv) : 0.0f;
    float basis[16];
    #pragma unroll
    for (int n = 0; n < 16; ++n)
      basis[n] = sinf((float)(n + 1) * PI_F * dist * (1.0f / CUT_F)) * bc;

    float h1[16];
    #pragma unroll
    for (int j = 0; j < 16; ++j) {
      float acc = 0.f;
      #pragma unroll
      for (int n = 0; n < 16; ++n) acc = fmaf(basis[n], w1s[n * 16 + j], acc);
      h1[j] = silu(acc * 0.25f);
    }

    float g1v[16], g4v[16];
    #pragma unroll
    for (int h = 0; h < 16; ++h) { g1v[h] = 0.f; g4v[h] = 0.f; }
    #pragma unroll
    for (int j = 0; j < 16; ++j) {
      float hj = h1[j];
      #pragma unroll
      for (int h = 0; h < 16; ++h) {
        g1v[h] = fmaf(hj, g1s[j * 16 + h], g1v[h]);
        g4v[h] = fmaf(hj, g4s[j * 16 + h], g4v[h]);
      }
    }

    const float* z0s = z0 + (size_t)s * 16;
    const float* z1s = z1 + (size_t)s * 48;
    float sg = 0.f, dg = 0.f;
    #pragma unroll
    for (int h = 0; h < 16; ++h) sg = fmaf(z0s[h], g1v[h], sg);
    #pragma unroll
    for (int h = 0; h < 16; ++h) {
      float dot = (z1s[h * 3 + 0] * ux + z1s[h * 3 + 1] * uy +
                   z1s[h * 3 + 2] * uz) * INV4PI_F;
      dg = fmaf(dot, g4v[h], dg);
    }
    // edge contribution to output: (n1/64) * (y0 * s.g1 + dot.g4)
    c = (INV4PI_F * sg + dg) * (N0_F * (1.0f / 64.0f));
  }
  float tot = block_reduce_sum(c);
  if (threadIdx.x == 0) atomicAdd(out, tot);
}

// ---------------------------------------------------------------------------
// Node readout: out += 0.25 * sum_n z0[n] . r
// ---------------------------------------------------------------------------
__global__ void node_readout_kernel(const float* __restrict__ z0,
                                    const float* __restrict__ w_readout,
                                    float* __restrict__ out,
                                    int N) {
  __shared__ float rs[16];
  if (threadIdx.x < 16) rs[threadIdx.x] = w_readout[threadIdx.x];
  __syncthreads();
  int n = blockIdx.x * blockDim.x + threadIdx.x;
  float c = 0.f;
  if (n < N) {
    const float* row = z0 + (size_t)n * 16;
    #pragma unroll
    for (int h = 0; h < 16; ++h) c = fmaf(row[h], rs[h], c);
    c *= 0.25f;
  }
  float tot = block_reduce_sum(c);
  if (threadIdx.x == 0) atomicAdd(out, tot);
}

extern "C" void kernel_launch(void* const* d_in, const int* in_sizes, int n_in,
                              void* d_out, int out_size, void* d_ws, size_t ws_size,
                              hipStream_t stream) {
  const int*   an        = (const int*)d_in[0];
  const float* coords    = (const float*)d_in[1];
  const int*   ei        = (const int*)d_in[2];
  const float* atom_emb  = (const float*)d_in[3];
  const float* fc0_w1    = (const float*)d_in[4];
  const float* fc0_w2    = (const float*)d_in[5];
  const float* fc1_w1    = (const float*)d_in[6];
  const float* fc1_w2    = (const float*)d_in[7];
  const float* w_readout = (const float*)d_in[8];

  int N = in_sizes[0];
  int E = in_sizes[2] / 2;

  float* ws = (float*)d_ws;
  float* z0 = ws;                    // N*16 floats
  float* z1 = z0 + (size_t)N * 16;   // N*48 floats
  float* T0 = z1 + (size_t)N * 48;   // 100*256
  float* T1 = T0 + NATOMS * 256;     // 100*256
  float* G1 = T1 + NATOMS * 256;     // 256
  float* G4 = G1 + 256;              // 256
  float* out = (float*)d_out;

  hipMemsetAsync(z0, 0, (size_t)N * 64 * sizeof(float), stream);
  hipMemsetAsync(out, 0, sizeof(float), stream);

  precompute_kernel<<<NATOMS + 1, 256, 0, stream>>>(
      atom_emb, fc0_w2, fc1_w2, w_readout, T0, T1, G1, G4);

  int blk = 256;
  int egrid = (E + blk - 1) / blk;
  phase1_kernel<<<egrid, blk, 0, stream>>>(ei, coords, an, fc0_w1, T0, T1,
                                           z0, z1, E);
  phase2_kernel<<<egrid, blk, 0, stream>>>(ei, coords, fc1_w1, G1, G4,
                                           z0, z1, out, E);
  node_readout_kernel<<<(N + blk - 1) / blk, blk, 0, stream>>>(
      z0, w_readout, out, N);
}

// Round 2
// 630.288 us; speedup vs baseline: 1.0404x; 1.0404x over previous
//
#include <hip/hip_runtime.h>
#include <math.h>

// EquiTritonModel: N=10000 nodes, E=160000 edges, D=32, H=16, NB=16.
// R1 -> R2: phase1 scatter-atomics (10.2M fp32 atomicAdds, 562us, VALUBusy
// 1.3%) replaced by CSR-by-dst build + one-wave-per-node register gather.
// z-buffer layout per node (64 floats): [z0 (16) | z1x (16) | z1y (16) | z1z (16)]
// (axis-major z1 so each lane computes u1[t] once, reuses for 3 axes).

namespace {
constexpr int   NATOMS   = 100;
constexpr float PI_F     = 3.14159265358979323846f;
constexpr float INV4PI_F = 0.28209479177387814f;   // 1/sqrt(4*pi)
constexpr float SQRT3_F  = 1.7320508075688772f;
constexpr float CUT_F    = 6.0f;
constexpr float BASIS_C  = 2.3094010767585034f;    // sqrt(2/6)*sqrt(16)
constexpr float N0_F     = 0.17677669529663687f;   // 1/sqrt(32)
// k0 = y0 * n0 * 0.25 (fc0 /sqrt(16)) * 0.25 (DEG); k1 = sqrt(3)*k0
constexpr float K0_F = INV4PI_F * N0_F * 0.0625f;
constexpr float K1_F = SQRT3_F * INV4PI_F * N0_F * 0.0625f;
}

__device__ __forceinline__ float silu_fast(float x) {
  return x / (1.0f + __expf(-x));
}

__device__ __forceinline__ float block_reduce_sum(float v) {
  #pragma unroll
  for (int o = 32; o > 0; o >>= 1) v += __shfl_down(v, o, 64);
  __shared__ float ls[8];
  int lane = threadIdx.x & 63;
  int w    = threadIdx.x >> 6;
  if (lane == 0) ls[w] = v;
  __syncthreads();
  float s = 0.f;
  if (threadIdx.x == 0) {
    int nw = (blockDim.x + 63) >> 6;
    for (int i = 0; i < nw; ++i) s += ls[i];
  }
  return s;
}

// ---------------------------------------------------------------------------
// Precompute: T0/T1[a,j,h] (100x16x16) and G1/G4[j,h] (16x16).
// ---------------------------------------------------------------------------
__global__ void precompute_kernel(const float* __restrict__ atom_emb,
                                  const float* __restrict__ fc0_w2,
                                  const float* __restrict__ fc1_w2,
                                  const float* __restrict__ w_readout,
                                  float* __restrict__ T0, float* __restrict__ T1,
                                  float* __restrict__ G1, float* __restrict__ G4) {
  int b = blockIdx.x;
  int t = threadIdx.x;           // t = j*16 + h
  int j = t >> 4;
  int h = t & 15;
  if (b < NATOMS) {
    float s0 = 0.f, s1 = 0.f;
    #pragma unroll
    for (int d = 0; d < 32; ++d) {
      float x = atom_emb[b * 32 + d];
      s0 = fmaf(x, fc0_w2[j * 1024 + d * 16 + h], s0);
      s1 = fmaf(x, fc0_w2[j * 1024 + 512 + d * 16 + h], s1);
    }
    T0[b * 256 + t] = s0;
    T1[b * 256 + t] = s1;
  } else {
    float g1 = 0.f, g4 = 0.f;
    #pragma unroll
    for (int k = 0; k < 16; ++k) {
      float r = w_readout[k];
      g1 = fmaf(fc1_w2[j * 1024 + h * 16 + k], r, g1);
      g4 = fmaf(fc1_w2[j * 1024 + 768 + h * 16 + k], r, g4);
    }
    G1[t] = g1;
    G4[t] = g4;
  }
}

// ---------------------------------------------------------------------------
// CSR build: count by dst, exclusive scan, bucket (store SRC node id).
// ---------------------------------------------------------------------------
__global__ void count_kernel(const int* __restrict__ ei, int* __restrict__ count,
                             int E) {
  int e = blockIdx.x * blockDim.x + threadIdx.x;
  if (e < E) atomicAdd(&count[ei[E + e]], 1);
}

__global__ void scan_kernel(const int* __restrict__ count,
                            int* __restrict__ start, int N) {
  __shared__ int bufA[1024];
  __shared__ int bufB[1024];
  int t = threadIdx.x;
  int chunk = (N + 1023) / 1024;
  int b0 = t * chunk;
  int s = 0;
  for (int i = 0; i < chunk; ++i) {
    int idx = b0 + i;
    if (idx < N) s += count[idx];
  }
  int* a = bufA; int* b = bufB;
  a[t] = s;
  __syncthreads();
  for (int off = 1; off < 1024; off <<= 1) {
    int v = a[t];
    if (t >= off) v += a[t - off];
    b[t] = v;
    __syncthreads();
    int* tmp = a; a = b; b = tmp;
  }
  int run = a[t] - s;   // exclusive prefix for this chunk
  for (int i = 0; i < chunk; ++i) {
    int idx = b0 + i;
    if (idx < N) { start[idx] = run; run += count[idx]; }
  }
  if (t == 0) start[N] = a[1023];
}

__global__ void bucket_kernel(const int* __restrict__ ei,
                              const int* __restrict__ start,
                              int* __restrict__ cursor,
                              int* __restrict__ elist, int E) {
  int e = blockIdx.x * blockDim.x + threadIdx.x;
  if (e < E) {
    int d = ei[E + e];
    int pos = atomicAdd(&cursor[d], 1);
    elist[start[d] + pos] = ei[e];   // store src id
  }
}

// ---------------------------------------------------------------------------
// Phase 1 (gather): one wave per node. 4 groups x 16 lanes; group g handles
// edges beg+g, beg+g+4, ...; lane t produces z0[t] and u1[t]*unit.
// ---------------------------------------------------------------------------
__global__ void gather_kernel(const int* __restrict__ elist,
                              const int* __restrict__ start,
                              const float* __restrict__ coords,
                              const int* __restrict__ an,
                              const float* __restrict__ fc0_w1,
                              const float* __restrict__ T0,
                              const float* __restrict__ T1,
                              float* __restrict__ zbuf,
                              int N) {
  __shared__ float w1s[256];
  w1s[threadIdx.x] = fc0_w1[threadIdx.x];
  __syncthreads();
  int wave = threadIdx.x >> 6;
  int lane = threadIdx.x & 63;
  int g = lane >> 4, t = lane & 15;
  int node = blockIdx.x * 4 + wave;
  if (node >= N) return;

  float cnx = coords[3 * node + 0];
  float cny = coords[3 * node + 1];
  float cnz = coords[3 * node + 2];
  int beg = start[node], end = start[node + 1];

  float acc0 = 0.f, accx = 0.f, accy = 0.f, accz = 0.f;
  for (int i = beg + g; i < end; i += 4) {
    int s = elist[i];
    float vx = coords[3 * s + 0] - cnx;
    float vy = coords[3 * s + 1] - cny;
    float vz = coords[3 * s + 2] - cnz;
    float dist = sqrtf(vx * vx + vy * vy + vz * vz);
    float inv  = 1.0f / fmaxf(dist, 1e-9f);
    float ux = vx * inv, uy = vy * inv, uz = vz * inv;
    float bc = (dist < CUT_F) ? (BASIS_C * inv) : 0.0f;

    float basis[16];
    #pragma unroll
    for (int k = 0; k < 16; ++k)
      basis[k] = __sinf((float)(k + 1) * (PI_F / CUT_F) * dist) * bc;

    float h0[16];
    #pragma unroll
    for (int j = 0; j < 16; ++j) {
      float acc = 0.f;
      #pragma unroll
      for (int k = 0; k < 16; ++k) acc = fmaf(basis[k], w1s[k * 16 + j], acc);
      h0[j] = silu_fast(acc * 0.25f);
    }

    int a = an[s];
    const float* t0 = T0 + a * 256 + t;
    const float* t1 = T1 + a * 256 + t;
    float u0 = 0.f, u1 = 0.f;
    #pragma unroll
    for (int j = 0; j < 16; ++j) {
      u0 = fmaf(h0[j], t0[j * 16], u0);
      u1 = fmaf(h0[j], t1[j * 16], u1);
    }
    acc0 += u0;
    accx = fmaf(u1, ux, accx);
    accy = fmaf(u1, uy, accy);
    accz = fmaf(u1, uz, accz);
  }
  // reduce the 4 groups (lanes t, 16+t, 32+t, 48+t)
  acc0 += __shfl_xor(acc0, 16, 64); acc0 += __shfl_xor(acc0, 32, 64);
  accx += __shfl_xor(accx, 16, 64); accx += __shfl_xor(accx, 32, 64);
  accy += __shfl_xor(accy, 16, 64); accy += __shfl_xor(accy, 32, 64);
  accz += __shfl_xor(accz, 16, 64); accz += __shfl_xor(accz, 32, 64);
  if (g == 0) {
    float* zb = zbuf + (size_t)node * 64;
    zb[t]      = acc0 * K0_F;
    zb[16 + t] = accx * K1_F;
    zb[32 + t] = accy * K1_F;
    zb[48 + t] = accz * K1_F;
  }
}

// ---------------------------------------------------------------------------
// Phase 2: per edge, basis -> h1, g1/g4 via G tables, gather z[src],
// block-reduce, one atomic per block. z1 is axis-major.
// ---------------------------------------------------------------------------
__global__ void phase2_kernel(const int* __restrict__ ei,
                              const float* __restrict__ coords,
                              const float* __restrict__ fc1_w1,
                              const float* __restrict__ G1t,
                              const float* __restrict__ G4t,
                              const float* __restrict__ zbuf,
                              float* __restrict__ out,
                              int E) {
  __shared__ float w1s[256];
  __shared__ float g1s[256];
  __shared__ float g4s[256];
  w1s[threadIdx.x] = fc1_w1[threadIdx.x];
  g1s[threadIdx.x] = G1t[threadIdx.x];
  g4s[threadIdx.x] = G4t[threadIdx.x];
  __syncthreads();

  int e = blockIdx.x * blockDim.x + threadIdx.x;
  float c = 0.f;
  if (e < E) {
    int s = ei[e];
    int d = ei[E + e];
    float vx = coords[3 * s + 0] - coords[3 * d + 0];
    float vy = coords[3 * s + 1] - coords[3 * d + 1];
    float vz = coords[3 * s + 2] - coords[3 * d + 2];
    float dist = sqrtf(vx * vx + vy * vy + vz * vz);
    float inv  = 1.0f / fmaxf(dist, 1e-9f);
    float ux = vx * inv, uy = vy * inv, uz = vz * inv;
    float bc = (dist < CUT_F) ? (BASIS_C * inv) : 0.0f;

    float basis[16];
    #pragma unroll
    for (int k = 0; k < 16; ++k)
      basis[k] = __sinf((float)(k + 1) * (PI_F / CUT_F) * dist) * bc;

    float h1[16];
    #pragma unroll
    for (int j = 0; j < 16; ++j) {
      float acc = 0.f;
      #pragma unroll
      for (int k = 0; k < 16; ++k) acc = fmaf(basis[k], w1s[k * 16 + j], acc);
      h1[j] = silu_fast(acc * 0.25f);
    }

    float g1v[16], g4v[16];
    #pragma unroll
    for (int h = 0; h < 16; ++h) { g1v[h] = 0.f; g4v[h] = 0.f; }
    #pragma unroll
    for (int j = 0; j < 16; ++j) {
      float hj = h1[j];
      #pragma unroll
      for (int h = 0; h < 16; ++h) {
        g1v[h] = fmaf(hj, g1s[j * 16 + h], g1v[h]);
        g4v[h] = fmaf(hj, g4s[j * 16 + h], g4v[h]);
      }
    }

    const float* zb = zbuf + (size_t)s * 64;
    float sg = 0.f, dg = 0.f;
    #pragma unroll
    for (int h = 0; h < 16; ++h) sg = fmaf(zb[h], g1v[h], sg);
    #pragma unroll
    for (int h = 0; h < 16; ++h) {
      float dot = (zb[16 + h] * ux + zb[32 + h] * uy + zb[48 + h] * uz) * INV4PI_F;
      dg = fmaf(dot, g4v[h], dg);
    }
    c = (INV4PI_F * sg + dg) * (N0_F * (1.0f / 64.0f));
  }
  float tot = block_reduce_sum(c);
  if (threadIdx.x == 0) atomicAdd(out, tot);
}

// ---------------------------------------------------------------------------
// Node readout: out += 0.25 * sum_n z0[n] . r
// ---------------------------------------------------------------------------
__global__ void node_readout_kernel(const float* __restrict__ zbuf,
                                    const float* __restrict__ w_readout,
                                    float* __restrict__ out,
                                    int N) {
  __shared__ float rs[16];
  if (threadIdx.x < 16) rs[threadIdx.x] = w_readout[threadIdx.x];
  __syncthreads();
  int n = blockIdx.x * blockDim.x + threadIdx.x;
  float c = 0.f;
  if (n < N) {
    const float* row = zbuf + (size_t)n * 64;
    #pragma unroll
    for (int h = 0; h < 16; ++h) c = fmaf(row[h], rs[h], c);
    c *= 0.25f;
  }
  float tot = block_reduce_sum(c);
  if (threadIdx.x == 0) atomicAdd(out, tot);
}

extern "C" void kernel_launch(void* const* d_in, const int* in_sizes, int n_in,
                              void* d_out, int out_size, void* d_ws, size_t ws_size,
                              hipStream_t stream) {
  const int*   an        = (const int*)d_in[0];
  const float* coords    = (const float*)d_in[1];
  const int*   ei        = (const int*)d_in[2];
  const float* atom_emb  = (const float*)d_in[3];
  const float* fc0_w1    = (const float*)d_in[4];
  const float* fc0_w2    = (const float*)d_in[5];
  const float* fc1_w1    = (const float*)d_in[6];
  const float* fc1_w2    = (const float*)d_in[7];
  const float* w_readout = (const float*)d_in[8];

  int N = in_sizes[0];
  int E = in_sizes[2] / 2;

  float* ws   = (float*)d_ws;
  float* zbuf = ws;                         // N*64 floats
  float* T0   = zbuf + (size_t)N * 64;      // 100*256
  float* T1   = T0 + NATOMS * 256;          // 100*256
  float* G1   = T1 + NATOMS * 256;          // 256
  float* G4   = G1 + 256;                   // 256
  int*   count  = (int*)(G4 + 256);         // N
  int*   cursor = count + N;                // N
  int*   startp = cursor + N;               // N+1
  int*   elist  = startp + N + 1;           // E
  float* out = (float*)d_out;

  hipMemsetAsync(count, 0, (size_t)2 * N * sizeof(int), stream);  // count+cursor
  hipMemsetAsync(out, 0, sizeof(float), stream);

  precompute_kernel<<<NATOMS + 1, 256, 0, stream>>>(
      atom_emb, fc0_w2, fc1_w2, w_readout, T0, T1, G1, G4);

  int blk = 256;
  int egrid = (E + blk - 1) / blk;
  count_kernel<<<egrid, blk, 0, stream>>>(ei, count, E);
  scan_kernel<<<1, 1024, 0, stream>>>(count, startp, N);
  bucket_kernel<<<egrid, blk, 0, stream>>>(ei, startp, cursor, elist, E);

  gather_kernel<<<(N + 3) / 4, 256, 0, stream>>>(
      elist, startp, coords, an, fc0_w1, T0, T1, zbuf, N);

  phase2_kernel<<<egrid, blk, 0, stream>>>(ei, coords, fc1_w1, G1, G4,
                                           zbuf, out, E);
  node_readout_kernel<<<(N + blk - 1) / blk, blk, 0, stream>>>(
      zbuf, w_readout, out, N);
}